// Round 4
// baseline (1394.388 us; speedup 1.0000x reference)
//
#include <hip/hip_runtime.h>

#define NC 128      // channels
#define NB 8        // batch
#define CPB 32      // channels per block
#define R 4         // consecutive j outputs per thread
#define JT (8 * R)  // j-tile width per block (threadIdx.y covers 8 runs)

// ---------------------------------------------------------------------------
// LL-only Haar downsample: P (NB, 2h, 2w, NC) -> out (NB, h, w, NC)
// ---------------------------------------------------------------------------
__global__ __launch_bounds__(256) void k_haar_ll(
    const float* __restrict__ P, float* __restrict__ out, int h, int w)
{
    int idx = blockIdx.x * blockDim.x + threadIdx.x;
    int total = NB * h * w * (NC / 4);
    if (idx >= total) return;
    int cq = idx & (NC / 4 - 1);
    int t  = idx / (NC / 4);
    int j  = t % w; t /= w;
    int i  = t % h;
    int b  = t / h;
    size_t W2C  = (size_t)(2 * w) * NC;
    size_t base = (((size_t)b * (2 * h) + 2 * i) * (2 * w) + 2 * j) * NC + cq * 4;
    float4 A  = *(const float4*)(P + base);
    float4 Bv = *(const float4*)(P + base + NC);
    float4 Cv = *(const float4*)(P + base + W2C);
    float4 Dv = *(const float4*)(P + base + W2C + NC);
    float4 r;
    r.x = (A.x + Bv.x + Cv.x + Dv.x) * 0.5f;
    r.y = (A.y + Bv.y + Cv.y + Dv.y) * 0.5f;
    r.z = (A.z + Bv.z + Cv.z + Dv.z) * 0.5f;
    r.w = (A.w + Bv.w + Cv.w + Dv.w) * 0.5f;
    *(float4*)(out + (size_t)idx * 4) = r;
}

// ---------------------------------------------------------------------------
// Fused conv-on-haar-subbands + inverse (+ base depthwise for level 0).
// Sliding-window: each thread produces R consecutive j outputs; each parent
// tap column (A,B,C,D) is loaded once and reused by up to 5 outputs.
// Branchless edges: per-column clamp + 0/1 mask (hoisted), uniform y-skip.
// blockDim = (32, 8). grid = ((w/JT)*4, h, NB). blockIdx.x = jtile*4 + cg.
// ---------------------------------------------------------------------------
#define WL(s, t)  wl[((s) * 25 + (t)) * CPB + tc]
#define WB(m, n)  wbase[((m) * 5 + (n)) * CPB + tc]

template <bool BASE>
__global__ __launch_bounds__(256, 4) void k_convinv(
    const float* __restrict__ P, const float* __restrict__ nll,
    const float* __restrict__ wk, const float* __restrict__ wsc,
    const float* __restrict__ bk, const float* __restrict__ bb,
    const float* __restrict__ bs, float* __restrict__ out,
    int h, int w)
{
    extern __shared__ float lds[];
    float* wl     = lds;               // [4][25][CPB]
    float* wbase  = wl + 4 * 25 * CPB; // [25][CPB]   (BASE)
    float* bscale = wbase + 25 * CPB;  // [CPB]       (BASE)
    float* bbias  = bscale + CPB;      // [CPB]       (BASE)

    const int cg    = blockIdx.x & 3;
    const int jtile = blockIdx.x >> 2;
    const int c0    = cg * CPB;
    const int tid   = threadIdx.x + threadIdx.y * 32;

    for (int u = tid; u < 4 * 25 * CPB; u += 256) {
        int tcc = u & (CPB - 1);
        int st  = u / CPB;
        int t   = st % 25;
        int s   = st / 25;
        wl[u] = 0.5f * wsc[(c0 + tcc) * 4 + s] * wk[t * (4 * NC) + (c0 + tcc) * 4 + s];
    }
    if (BASE) {
        for (int u = tid; u < 25 * CPB; u += 256) {
            int tcc = u & (CPB - 1);
            int t   = u / CPB;
            wbase[u] = bk[t * NC + c0 + tcc];
        }
        if (tid < CPB) { bscale[tid] = bs[c0 + tid]; bbias[tid] = bb[c0 + tid]; }
    }
    __syncthreads();

    const int tc = threadIdx.x;
    const int c  = c0 + tc;
    const int b  = blockIdx.z;
    const int i  = blockIdx.y;
    const int ja = jtile * JT + threadIdx.y * R;   // first output j of thread
    const int PH = 2 * h;
    const size_t rowC = (size_t)(2 * w) * NC;

    // Per-column clamped element offsets + validity masks (q index 0..R+3,
    // actual column = ja + q - 2).
    int   coff[R + 4];
    float cmask[R + 4];
    #pragma unroll
    for (int q = 0; q < R + 4; ++q) {
        int xq  = ja + q - 2;
        int xqc = min(max(xq, 0), w - 1);
        coff[q]  = xqc * (2 * NC);
        cmask[q] = (xq >= 0 && xq < w) ? 1.f : 0.f;
    }

    float acc0[R], acc1[R], acc2[R], acc3[R];
    float bb00[R], bb01[R], bb10[R], bb11[R];
    #pragma unroll
    for (int s = 0; s < R; ++s) {
        acc0[s] = acc1[s] = acc2[s] = acc3[s] = 0.f;
        bb00[s] = bb01[s] = bb10[s] = bb11[s] = 0.f;
    }

    #pragma unroll
    for (int ky = 0; ky < 5; ++ky) {
        int y = i + ky - 2;
        if (y < 0 || y >= h) continue;          // block-uniform branch
        const float* prA = P + ((size_t)b * PH + 2 * y) * rowC + c;
        const float* prC = prA + rowC;
        #pragma unroll
        for (int q = 0; q < R + 4; ++q) {
            float m = cmask[q];
            const float* pA = prA + coff[q];
            const float* pC = prC + coff[q];
            float A  = pA[0]  * m;
            float Bv = pA[NC] * m;
            float Cv = pC[0]  * m;
            float Dv = pC[NC] * m;
            float sA = A + Bv, sC = Cv + Dv;
            float dA = A - Bv, dC = Cv - Dv;
            float s0 = sA + sC, s1 = sA - sC, s2 = dA + dC, s3 = dA - dC;
            #pragma unroll
            for (int s = 0; s < R; ++s) {
                const int kx = q - s;          // tap index for output s
                if (kx < 0 || kx > 4) continue;
                const int t = ky * 5 + kx;
                acc0[s] += s0 * WL(0, t);
                acc1[s] += s1 * WL(1, t);
                acc2[s] += s2 * WL(2, t);
                acc3[s] += s3 * WL(3, t);
                if (BASE && ky >= 1 && ky <= 3 && kx >= 1 && kx <= 3) {
                    bb00[s] += A * WB(2 * ky - 2, 2 * kx - 2);
                    if (kx >= 2)            bb01[s] += A  * WB(2 * ky - 2, 2 * kx - 3);
                    if (ky >= 2)            bb10[s] += A  * WB(2 * ky - 3, 2 * kx - 2);
                    if (ky >= 2 && kx >= 2) bb11[s] += A  * WB(2 * ky - 3, 2 * kx - 3);
                    if (kx <= 2)            bb00[s] += Bv * WB(2 * ky - 2, 2 * kx - 1);
                                            bb01[s] += Bv * WB(2 * ky - 2, 2 * kx - 2);
                    if (ky >= 2 && kx <= 2) bb10[s] += Bv * WB(2 * ky - 3, 2 * kx - 1);
                    if (ky >= 2)            bb11[s] += Bv * WB(2 * ky - 3, 2 * kx - 2);
                    if (ky <= 2)            bb00[s] += Cv * WB(2 * ky - 1, 2 * kx - 2);
                    if (ky <= 2 && kx >= 2) bb01[s] += Cv * WB(2 * ky - 1, 2 * kx - 3);
                                            bb10[s] += Cv * WB(2 * ky - 2, 2 * kx - 2);
                    if (kx >= 2)            bb11[s] += Cv * WB(2 * ky - 2, 2 * kx - 3);
                    if (ky <= 2 && kx <= 2) bb00[s] += Dv * WB(2 * ky - 1, 2 * kx - 1);
                    if (ky <= 2)            bb01[s] += Dv * WB(2 * ky - 1, 2 * kx - 2);
                    if (kx <= 2)            bb10[s] += Dv * WB(2 * ky - 2, 2 * kx - 1);
                                            bb11[s] += Dv * WB(2 * ky - 2, 2 * kx - 2);
                }
            }
        }
    }

    #pragma unroll
    for (int s = 0; s < R; ++s) {
        int j = ja + s;
        float a0 = acc0[s];
        if (nll) a0 += nll[(((size_t)b * h + i) * w + j) * NC + c];
        float av = (a0 + acc1[s] + acc2[s] + acc3[s]) * 0.5f;
        float bv = (a0 + acc1[s] - acc2[s] - acc3[s]) * 0.5f;
        float cv = (a0 - acc1[s] + acc2[s] - acc3[s]) * 0.5f;
        float dv = (a0 - acc1[s] - acc2[s] + acc3[s]) * 0.5f;

        size_t ob = ((size_t)b * PH + 2 * i) * rowC + (size_t)(2 * j) * NC + c;
        if (BASE) {
            float sc = bscale[tc], bi = bbias[tc];
            out[ob]             = sc * (bb00[s] + bi) + av;
            out[ob + NC]        = sc * (bb01[s] + bi) + bv;
            out[ob + rowC]      = sc * (bb10[s] + bi) + cv;
            out[ob + rowC + NC] = sc * (bb11[s] + bi) + dv;
        } else {
            out[ob]             = av;
            out[ob + NC]        = bv;
            out[ob + rowC]      = cv;
            out[ob + rowC + NC] = dv;
        }
    }
}

// ---------------------------------------------------------------------------
extern "C" void kernel_launch(void* const* d_in, const int* in_sizes, int n_in,
                              void* d_out, int out_size, void* d_ws, size_t ws_size,
                              hipStream_t stream)
{
    const float* x  = (const float*)d_in[0];
    const float* bk = (const float*)d_in[1];
    const float* bb = (const float*)d_in[2];
    const float* bs = (const float*)d_in[3];
    const float* wk[3];
    const float* wv[3];
    if (n_in >= 10) {
        for (int i = 0; i < 3; ++i) {
            wk[i] = (const float*)d_in[4 + i];
            wv[i] = (const float*)d_in[7 + i];
        }
    } else {
        const float* wkc = (const float*)d_in[4];
        const float* wvc = (const float*)d_in[5];
        for (int i = 0; i < 3; ++i) {
            wk[i] = wkc + (size_t)i * 25 * 4 * NC;
            wv[i] = wvc + (size_t)i * 4 * NC;
        }
    }
    float* out = (float*)d_out;

    // Dead-before-final intermediates live inside d_out (fully rewritten by
    // the final kernel). r1 (read during final pass) lives in d_ws.
    float* ll0 = out;                       // (8,128,128,128)
    float* ll1 = out + 16777216;            // (8, 64, 64,128)
    float* r2  = out + 16777216 + 4194304;  // (8, 64, 64,128)
    float* r1  = (float*)d_ws;              // (8,128,128,128) = 64 MiB

    // 1) x -> ll0
    {
        int total = NB * 128 * 128 * (NC / 4);
        k_haar_ll<<<(total + 255) / 256, 256, 0, stream>>>(x, ll0, 128, 128);
    }
    // 2) ll0 -> ll1
    {
        int total = NB * 64 * 64 * (NC / 4);
        k_haar_ll<<<(total + 255) / 256, 256, 0, stream>>>(ll0, ll1, 64, 64);
    }

    size_t lds_nb = (size_t)(4 * 25 * CPB) * sizeof(float);                      // 12800 B
    size_t lds_b  = (size_t)(4 * 25 * CPB + 25 * CPB + 2 * CPB) * sizeof(float); // 16256 B
    dim3 blk(32, 8);

    // 3) level 2: ll1 -> r2   (coeff grid 32x32)
    k_convinv<false><<<dim3((32 / JT) * 4, 32, NB), blk, lds_nb, stream>>>(
        ll1, nullptr, wk[2], wv[2], nullptr, nullptr, nullptr, r2, 32, 32);

    // 4) level 1: ll0 (+r2) -> r1   (coeff grid 64x64)
    k_convinv<false><<<dim3((64 / JT) * 4, 64, NB), blk, lds_nb, stream>>>(
        ll0, r2, wk[1], wv[1], nullptr, nullptr, nullptr, r1, 64, 64);

    // 5) level 0: x (+r1) + base path -> d_out   (coeff grid 128x128)
    k_convinv<true><<<dim3((128 / JT) * 4, 128, NB), blk, lds_b, stream>>>(
        x, r1, wk[0], wv[0], bk, bb, bs, out, 128, 128);
}

// Round 5
// 710.272 us; speedup vs baseline: 1.9632x; 1.9632x over previous
//
#include <hip/hip_runtime.h>

#define NC 128      // channels
#define NB 8        // batch
#define CPB 32      // channels per block
#define R 2         // consecutive j outputs per thread
#define JT (8 * R)  // j-tile width per block (threadIdx.y covers 8 runs)

// ---------------------------------------------------------------------------
// LL-only Haar downsample: P (NB, 2h, 2w, NC) -> out (NB, h, w, NC)
// ---------------------------------------------------------------------------
__global__ __launch_bounds__(256) void k_haar_ll(
    const float* __restrict__ P, float* __restrict__ out, int h, int w)
{
    int idx = blockIdx.x * blockDim.x + threadIdx.x;
    int total = NB * h * w * (NC / 4);
    if (idx >= total) return;
    int cq = idx & (NC / 4 - 1);
    int t  = idx / (NC / 4);
    int j  = t % w; t /= w;
    int i  = t % h;
    int b  = t / h;
    size_t W2C  = (size_t)(2 * w) * NC;
    size_t base = (((size_t)b * (2 * h) + 2 * i) * (2 * w) + 2 * j) * NC + cq * 4;
    float4 A  = *(const float4*)(P + base);
    float4 Bv = *(const float4*)(P + base + NC);
    float4 Cv = *(const float4*)(P + base + W2C);
    float4 Dv = *(const float4*)(P + base + W2C + NC);
    float4 r;
    r.x = (A.x + Bv.x + Cv.x + Dv.x) * 0.5f;
    r.y = (A.y + Bv.y + Cv.y + Dv.y) * 0.5f;
    r.z = (A.z + Bv.z + Cv.z + Dv.z) * 0.5f;
    r.w = (A.w + Bv.w + Cv.w + Dv.w) * 0.5f;
    *(float4*)(out + (size_t)idx * 4) = r;
}

// ---------------------------------------------------------------------------
// Fused conv-on-haar-subbands + inverse (+ base depthwise for level 0).
// Sliding window over j (R outputs/thread); per-ky weights staged LDS->regs
// once and reused across the whole row; all inner FMAs are register-operand.
// blockDim = (32, 8). grid = ((w/JT)*4, h, NB). blockIdx.x = jtile*4 + cg.
// ---------------------------------------------------------------------------
#define WL(s, t)  wl[((s) * 25 + (t)) * CPB + tc]
#define WB(m, n)  wbase[((m) * 5 + (n)) * CPB + tc]

template <bool BASE>
__global__ __launch_bounds__(256) void k_convinv(
    const float* __restrict__ P, const float* __restrict__ nll,
    const float* __restrict__ wk, const float* __restrict__ wsc,
    const float* __restrict__ bk, const float* __restrict__ bb,
    const float* __restrict__ bs, float* __restrict__ out,
    int h, int w)
{
    extern __shared__ float lds[];
    float* wl     = lds;               // [4][25][CPB]
    float* wbase  = wl + 4 * 25 * CPB; // [25][CPB]   (BASE)
    float* bscale = wbase + 25 * CPB;  // [CPB]       (BASE)
    float* bbias  = bscale + CPB;      // [CPB]       (BASE)

    const int cg    = blockIdx.x & 3;
    const int jtile = blockIdx.x >> 2;
    const int c0    = cg * CPB;
    const int tid   = threadIdx.x + threadIdx.y * 32;

    for (int u = tid; u < 4 * 25 * CPB; u += 256) {
        int tcc = u & (CPB - 1);
        int st  = u / CPB;
        int t   = st % 25;
        int s   = st / 25;
        wl[u] = 0.5f * wsc[(c0 + tcc) * 4 + s] * wk[t * (4 * NC) + (c0 + tcc) * 4 + s];
    }
    if (BASE) {
        for (int u = tid; u < 25 * CPB; u += 256) {
            int tcc = u & (CPB - 1);
            int t   = u / CPB;
            wbase[u] = bk[t * NC + c0 + tcc];
        }
        if (tid < CPB) { bscale[tid] = bs[c0 + tid]; bbias[tid] = bb[c0 + tid]; }
    }
    __syncthreads();

    const int tc = threadIdx.x;
    const int c  = c0 + tc;
    const int b  = blockIdx.z;
    const int i  = blockIdx.y;
    const int ja = jtile * JT + threadIdx.y * R;   // first output j of thread
    const int PH = 2 * h;
    const size_t rowC = (size_t)(2 * w) * NC;

    // Per-column clamped element offsets + validity masks (col = ja + q - 2).
    int   coff[R + 4];
    float cmask[R + 4];
    #pragma unroll
    for (int q = 0; q < R + 4; ++q) {
        int xq  = ja + q - 2;
        int xqc = min(max(xq, 0), w - 1);
        coff[q]  = xqc * (2 * NC);
        cmask[q] = (xq >= 0 && xq < w) ? 1.f : 0.f;
    }

    float acc0[R], acc1[R], acc2[R], acc3[R];
    float bb00[R], bb01[R], bb10[R], bb11[R];
    #pragma unroll
    for (int s = 0; s < R; ++s) {
        acc0[s] = acc1[s] = acc2[s] = acc3[s] = 0.f;
        bb00[s] = bb01[s] = bb10[s] = bb11[s] = 0.f;
    }

    #pragma unroll
    for (int ky = 0; ky < 5; ++ky) {
        int y = i + ky - 2;
        if (y < 0 || y >= h) continue;          // block-uniform branch

        // Stage this ky-row's weights into registers (reused across all q).
        float w0[5], w1[5], w2[5], w3[5];
        #pragma unroll
        for (int kx = 0; kx < 5; ++kx) {
            const int t = ky * 5 + kx;
            w0[kx] = WL(0, t); w1[kx] = WL(1, t);
            w2[kx] = WL(2, t); w3[kx] = WL(3, t);
        }
        // Base weight rows touched at this ky: index 0 -> row 2ky-3 (ky>=2),
        // 1 -> row 2ky-2, 2 -> row 2ky-1 (ky<=2).
        float wbr[3][5];
        if (BASE && ky >= 1 && ky <= 3) {
            #pragma unroll
            for (int n = 0; n < 5; ++n) {
                if (ky >= 2) wbr[0][n] = WB(2 * ky - 3, n);
                wbr[1][n] = WB(2 * ky - 2, n);
                if (ky <= 2) wbr[2][n] = WB(2 * ky - 1, n);
            }
        }

        const float* prA = P + ((size_t)b * PH + 2 * y) * rowC + c;
        const float* prC = prA + rowC;
        #pragma unroll
        for (int q = 0; q < R + 4; ++q) {
            float m = cmask[q];
            const float* pA = prA + coff[q];
            const float* pC = prC + coff[q];
            float A  = pA[0]  * m;
            float Bv = pA[NC] * m;
            float Cv = pC[0]  * m;
            float Dv = pC[NC] * m;
            float sA = A + Bv, sC = Cv + Dv;
            float dA = A - Bv, dC = Cv - Dv;
            float s0 = sA + sC, s1 = sA - sC, s2 = dA + dC, s3 = dA - dC;
            #pragma unroll
            for (int s = 0; s < R; ++s) {
                const int kx = q - s;          // tap index for output s
                if (kx < 0 || kx > 4) continue;
                acc0[s] += s0 * w0[kx];
                acc1[s] += s1 * w1[kx];
                acc2[s] += s2 * w2[kx];
                acc3[s] += s3 * w3[kx];
                if (BASE && ky >= 1 && ky <= 3 && kx >= 1 && kx <= 3) {
                    bb00[s] += A * wbr[1][2 * kx - 2];
                    if (kx >= 2)            bb01[s] += A  * wbr[1][2 * kx - 3];
                    if (ky >= 2)            bb10[s] += A  * wbr[0][2 * kx - 2];
                    if (ky >= 2 && kx >= 2) bb11[s] += A  * wbr[0][2 * kx - 3];
                    if (kx <= 2)            bb00[s] += Bv * wbr[1][2 * kx - 1];
                                            bb01[s] += Bv * wbr[1][2 * kx - 2];
                    if (ky >= 2 && kx <= 2) bb10[s] += Bv * wbr[0][2 * kx - 1];
                    if (ky >= 2)            bb11[s] += Bv * wbr[0][2 * kx - 2];
                    if (ky <= 2)            bb00[s] += Cv * wbr[2][2 * kx - 2];
                    if (ky <= 2 && kx >= 2) bb01[s] += Cv * wbr[2][2 * kx - 3];
                                            bb10[s] += Cv * wbr[1][2 * kx - 2];
                    if (kx >= 2)            bb11[s] += Cv * wbr[1][2 * kx - 3];
                    if (ky <= 2 && kx <= 2) bb00[s] += Dv * wbr[2][2 * kx - 1];
                    if (ky <= 2)            bb01[s] += Dv * wbr[2][2 * kx - 2];
                    if (kx <= 2)            bb10[s] += Dv * wbr[1][2 * kx - 1];
                                            bb11[s] += Dv * wbr[1][2 * kx - 2];
                }
            }
        }
    }

    #pragma unroll
    for (int s = 0; s < R; ++s) {
        int j = ja + s;
        float a0 = acc0[s];
        if (nll) a0 += nll[(((size_t)b * h + i) * w + j) * NC + c];
        float av = (a0 + acc1[s] + acc2[s] + acc3[s]) * 0.5f;
        float bv = (a0 + acc1[s] - acc2[s] - acc3[s]) * 0.5f;
        float cv = (a0 - acc1[s] + acc2[s] - acc3[s]) * 0.5f;
        float dv = (a0 - acc1[s] - acc2[s] + acc3[s]) * 0.5f;

        size_t ob = ((size_t)b * PH + 2 * i) * rowC + (size_t)(2 * j) * NC + c;
        if (BASE) {
            float sc = bscale[tc], bi = bbias[tc];
            out[ob]             = sc * (bb00[s] + bi) + av;
            out[ob + NC]        = sc * (bb01[s] + bi) + bv;
            out[ob + rowC]      = sc * (bb10[s] + bi) + cv;
            out[ob + rowC + NC] = sc * (bb11[s] + bi) + dv;
        } else {
            out[ob]             = av;
            out[ob + NC]        = bv;
            out[ob + rowC]      = cv;
            out[ob + rowC + NC] = dv;
        }
    }
}

// ---------------------------------------------------------------------------
extern "C" void kernel_launch(void* const* d_in, const int* in_sizes, int n_in,
                              void* d_out, int out_size, void* d_ws, size_t ws_size,
                              hipStream_t stream)
{
    const float* x  = (const float*)d_in[0];
    const float* bk = (const float*)d_in[1];
    const float* bb = (const float*)d_in[2];
    const float* bs = (const float*)d_in[3];
    const float* wk[3];
    const float* wv[3];
    if (n_in >= 10) {
        for (int i = 0; i < 3; ++i) {
            wk[i] = (const float*)d_in[4 + i];
            wv[i] = (const float*)d_in[7 + i];
        }
    } else {
        const float* wkc = (const float*)d_in[4];
        const float* wvc = (const float*)d_in[5];
        for (int i = 0; i < 3; ++i) {
            wk[i] = wkc + (size_t)i * 25 * 4 * NC;
            wv[i] = wvc + (size_t)i * 4 * NC;
        }
    }
    float* out = (float*)d_out;

    // Dead-before-final intermediates live inside d_out (fully rewritten by
    // the final kernel). r1 (read during final pass) lives in d_ws.
    float* ll0 = out;                       // (8,128,128,128)
    float* ll1 = out + 16777216;            // (8, 64, 64,128)
    float* r2  = out + 16777216 + 4194304;  // (8, 64, 64,128)
    float* r1  = (float*)d_ws;              // (8,128,128,128) = 64 MiB

    // 1) x -> ll0
    {
        int total = NB * 128 * 128 * (NC / 4);
        k_haar_ll<<<(total + 255) / 256, 256, 0, stream>>>(x, ll0, 128, 128);
    }
    // 2) ll0 -> ll1
    {
        int total = NB * 64 * 64 * (NC / 4);
        k_haar_ll<<<(total + 255) / 256, 256, 0, stream>>>(ll0, ll1, 64, 64);
    }

    size_t lds_nb = (size_t)(4 * 25 * CPB) * sizeof(float);                      // 12800 B
    size_t lds_b  = (size_t)(4 * 25 * CPB + 25 * CPB + 2 * CPB) * sizeof(float); // 16256 B
    dim3 blk(32, 8);

    // 3) level 2: ll1 -> r2   (coeff grid 32x32)
    k_convinv<false><<<dim3((32 / JT) * 4, 32, NB), blk, lds_nb, stream>>>(
        ll1, nullptr, wk[2], wv[2], nullptr, nullptr, nullptr, r2, 32, 32);

    // 4) level 1: ll0 (+r2) -> r1   (coeff grid 64x64)
    k_convinv<false><<<dim3((64 / JT) * 4, 64, NB), blk, lds_nb, stream>>>(
        ll0, r2, wk[1], wv[1], nullptr, nullptr, nullptr, r1, 64, 64);

    // 5) level 0: x (+r1) + base path -> d_out   (coeff grid 128x128)
    k_convinv<true><<<dim3((128 / JT) * 4, 128, NB), blk, lds_b, stream>>>(
        x, r1, wk[0], wv[0], bk, bb, bs, out, 128, 128);
}